// Round 15
// baseline (180.173 us; speedup 1.0000x reference)
//
#include <hip/hip_runtime.h>
#include <cstdint>
#include <cstddef>

typedef __bf16 bf16_t;
typedef __bf16 bf16x8 __attribute__((ext_vector_type(8)));
typedef float f32x4 __attribute__((ext_vector_type(4)));

#define MFMA16(a, b, c) __builtin_amdgcn_mfma_f32_16x16x32_bf16((a), (b), (c), 0, 0, 0)

// ---------------- fused f32 -> bf16 conversion (RNE), one launch ----------
// grid.y: 0..7 = x chunks (1M floats each), 8..10 = Wq/Wk/Wv, 11 = Wo.
__global__ __launch_bounds__(256) void cvt_all(const float* __restrict__ x,
                                               const float* __restrict__ Wq,
                                               const float* __restrict__ Wk,
                                               const float* __restrict__ Wv,
                                               const float* __restrict__ Wo,
                                               bf16_t* __restrict__ xb,
                                               bf16_t* __restrict__ wb,
                                               bf16_t* __restrict__ wob) {
  const int y = blockIdx.y;
  const float* src;
  bf16_t* dst;
  if (y < 8) {
    src = x + (size_t)y * 1048576;
    dst = xb + (size_t)y * 1048576;
  } else if (y == 8)  { src = Wq; dst = wb; }
  else if (y == 9)    { src = Wk; dst = wb + 1048576; }
  else if (y == 10)   { src = Wv; dst = wb + 2097152; }
  else                { src = Wo; dst = wob; }
  const int n4 = 262144;
  int stride = gridDim.x * blockDim.x;
  for (int i = blockIdx.x * blockDim.x + threadIdx.x; i < n4; i += stride) {
    float4 v = *(const float4*)(src + (size_t)i * 4);
    ushort4 o;
    o.x = __builtin_bit_cast(unsigned short, (bf16_t)v.x);
    o.y = __builtin_bit_cast(unsigned short, (bf16_t)v.y);
    o.z = __builtin_bit_cast(unsigned short, (bf16_t)v.z);
    o.w = __builtin_bit_cast(unsigned short, (bf16_t)v.w);
    *(ushort4*)(dst + (size_t)i * 4) = o;
  }
}

// ---------------- shared helpers ----------------
__device__ __forceinline__ void gload_lds16(const bf16_t* g, bf16_t* lds) {
  __builtin_amdgcn_global_load_lds(
      (const __attribute__((address_space(1))) unsigned int*)g,
      (__attribute__((address_space(3))) unsigned int*)lds, 16, 0, 0);
}

// tile pitch = 128 B per row; 16B granules XOR-swizzled by (row&7)
__device__ __forceinline__ bf16x8 lds_frag(const bf16_t* tile, int row, int g) {
  int byte = row * 128 + ((g ^ (row & 7)) << 4);
  return *(const bf16x8*)((const char*)tile + byte);
}

__device__ __forceinline__ unsigned cvt_pk_bf16(float lo, float hi) {
  unsigned r;
  asm("v_cvt_pk_bf16_f32 %0, %1, %2" : "=v"(r) : "v"(lo), "v"(hi));
  return r;
}

// ---------------- GEMM: C[M,N] = A[M,K] * B[N,K]^T, bf16 in, f32 acc ------
// r11-verified staging (A+B via gload_lds + XOR swizzle) + r13-verified
// within-XCD m-FAST ordering: each XCD owns 8 contiguous M-rows; the
// concurrent block window spans 8 M x ~6 N tiles -> A(2MB)+B(1.5MB) fit
// the 4MB per-XCD L2 (FETCH 84 -> 49MB measured).
template <int EPI>
__global__ __launch_bounds__(256)
void gemm_bt(const bf16_t* __restrict__ A, const bf16_t* __restrict__ Bm,
             bf16_t* __restrict__ Qo, bf16_t* __restrict__ Ko,
             bf16_t* __restrict__ Vto, float* __restrict__ Co) {
  const int K = 1024;
  __shared__ bf16_t As[128 * 64];
  __shared__ bf16_t Bs[128 * 64];
  const int wave = threadIdx.x >> 6, lane = threadIdx.x & 63;
  const int lm = lane & 15, lg = lane >> 4;
  const int wm = wave >> 1, wn = wave & 1;

  // bijective: xcd 0..7 owns M-rows [xcd*8, xcd*8+8), walked m-fastest
  const int xcd = blockIdx.x & 7;
  const int local = blockIdx.x >> 3;
  const int tm = (xcd * 8 + (local & 7)) * 128;
  const int tn = (local >> 3) * 128;

  f32x4 zero = {0.f, 0.f, 0.f, 0.f};
  f32x4 acc[4][4];
#pragma unroll
  for (int i = 0; i < 4; ++i)
#pragma unroll
    for (int j = 0; j < 4; ++j) acc[i][j] = zero;

  const int srow = lane >> 3;
  const int gs = lane & 7;

  for (int k0 = 0; k0 < K; k0 += 64) {
#pragma unroll
    for (int c = 0; c < 4; ++c) {
      int cc = wave * 4 + c;
      int row = cc * 8 + srow;
      int gsrc = gs ^ (row & 7);
      gload_lds16(A + (size_t)(tm + row) * K + k0 + gsrc * 8, &As[cc * 512]);
      gload_lds16(Bm + (size_t)(tn + row) * K + k0 + gsrc * 8, &Bs[cc * 512]);
    }
    __syncthreads();
#pragma unroll
    for (int kk = 0; kk < 2; ++kk) {
      bf16x8 af[4], bfr[4];
#pragma unroll
      for (int i = 0; i < 4; ++i) af[i] = lds_frag(As, wm * 64 + i * 16 + lm, kk * 4 + lg);
#pragma unroll
      for (int i = 0; i < 4; ++i) bfr[i] = lds_frag(Bs, wn * 64 + i * 16 + lm, kk * 4 + lg);
#pragma unroll
      for (int mi = 0; mi < 4; ++mi)
#pragma unroll
        for (int ni = 0; ni < 4; ++ni)
          acc[mi][ni] = MFMA16(af[mi], bfr[ni], acc[mi][ni]);
    }
    __syncthreads();
  }

#pragma unroll
  for (int mi = 0; mi < 4; ++mi) {
#pragma unroll
    for (int ni = 0; ni < 4; ++ni) {
      const int m0 = tm + wm * 64 + mi * 16 + lg * 4;  // 4-aligned, r = 0..3
      const int n = tn + wn * 64 + ni * 16 + lm;
      if (EPI == 0) {
        int which = n >> 10, rem = n & 1023;
        int hh = rem >> 6, d = rem & 63;
        int bb = m0 >> 11, s0 = m0 & 2047;  // all 4 r share bb (4 | 2048)
        size_t bh = (size_t)bb * 16 + hh;
        if (which == 2) {
          // V^T: the 4 r-values are consecutive in s -> one 8B store
          uint2 pw;
          pw.x = cvt_pk_bf16(acc[mi][ni][0], acc[mi][ni][1]);
          pw.y = cvt_pk_bf16(acc[mi][ni][2], acc[mi][ni][3]);
          *(uint2*)(Vto + (bh * 64 + d) * 2048 + s0) = pw;
        } else {
#pragma unroll
          for (int r = 0; r < 4; ++r) {
            float v = acc[mi][ni][r];
            if (which == 0)
              Qo[(bh * 2048 + s0 + r) * 64 + d] = (bf16_t)(v * 0.18033688011112042f);
            else
              Ko[(bh * 2048 + s0 + r) * 64 + d] = (bf16_t)v;
          }
        }
      } else {
#pragma unroll
        for (int r = 0; r < 4; ++r) Co[(size_t)(m0 + r) * 1024 + n] = acc[mi][ni][r];
      }
    }
  }
}

// ---------------- causal flash attention, swapped-QK^T layout ------------
// r14-verified: 8-wave blocks, 2 pair-groups sharing LDS-staged K/V, dbuf,
// counted vmcnt, raw barriers, plain-exp2 softmax. This round:
//  - ADJACENT pair grouping (p = 2j, 2j+1): group-1 idle shrinks 8 -> 1 tile
//  - s_setprio(1) around the MFMA clusters (T5, attn-positive per m191)
__device__ __forceinline__ void sm_step(const f32x4& s0, const f32x4& s1,
                                        float& l_run, bf16_t* P, int gbase,
                                        bool diag, int lm, int lg, int qrel) {
  float tv[2][4];
#pragma unroll
  for (int nt = 0; nt < 2; ++nt)
#pragma unroll
    for (int r = 0; r < 4; ++r) {
      float v = nt ? s1[r] : s0[r];
      if (diag && (nt * 16 + lg * 4 + r > qrel)) v = -3.0e38f;
      tv[nt][r] = v;
    }
#pragma unroll
  for (int nt = 0; nt < 2; ++nt) {
    float p0 = __builtin_amdgcn_exp2f(tv[nt][0]);
    float p1 = __builtin_amdgcn_exp2f(tv[nt][1]);
    float p2 = __builtin_amdgcn_exp2f(tv[nt][2]);
    float p3 = __builtin_amdgcn_exp2f(tv[nt][3]);
    l_run += (p0 + p1) + (p2 + p3);  // per-lane partial; reduced in epilogue
    uint2 pw;
    pw.x = cvt_pk_bf16(p0, p1);
    pw.y = cvt_pk_bf16(p2, p3);
    int gr = (gbase + nt * 2 + (lg >> 1)) ^ (lm & 7);
    *(uint2*)((char*)P + lm * 128 + gr * 16 + (lg & 1) * 8) = pw;
  }
}

__device__ __forceinline__ void pv_step(const bf16_t* P, int gbase, const bf16x8 bv[4],
                                        f32x4* acc, int lm, int lg) {
  int gr = (gbase + lg) ^ (lm & 7);
  bf16x8 pf = *(const bf16x8*)((const char*)P + lm * 128 + gr * 16);
#pragma unroll
  for (int nd = 0; nd < 4; ++nd) acc[nd] = MFMA16(bv[nd], pf, acc[nd]);
}

__global__ __launch_bounds__(512, 8)
void attn_fwd(const bf16_t* __restrict__ Q, const bf16_t* __restrict__ K,
              const bf16_t* __restrict__ Vt, bf16_t* __restrict__ Aout) {
  const int S = 2048;
  const int i = blockIdx.x;
  // XCD-locality decode: the 8 j-blocks of one bh land on the same XCD
  const int bh = (i & 7) * 8 + ((i >> 3) & 7);
  const int j = i >> 6;            // 0..7
  const int b = bh >> 4, h = bh & 15;
  const int w = threadIdx.x >> 6, lane = threadIdx.x & 63;
  const int lm = lane & 15, lg = lane >> 4;
  const int g = w >> 2;            // pair-group: waves 0-3 -> p=2j, 4-7 -> 2j+1
  const int wg = w & 3;            // wave-in-group (16 q-rows each)
  const int p = 2 * j + g;         // pair 0..15 (adjacent grouping)
  const int hL = p, hH = 31 - p;   // paired 64-row q-tiles (balanced work)
  const int qrowL = hL * 64 + wg * 16;
  const int qrowH = hH * 64 + wg * 16;
  const int qrel = ((wg & 1) << 4) + lm;  // q - kv0 at the diagonal step

  const bf16_t* Qb = Q + (size_t)bh * S * 64;
  const bf16_t* Kb = K + (size_t)bh * S * 64;
  const bf16_t* Vb = Vt + (size_t)bh * 64 * S;

  __shared__ bf16_t Plds[8][1024];   // per-wave P; L = granules 0-3, H = 4-7
  __shared__ bf16_t Ksb[2][4096];    // K tile [64 kv][64 d], dbuf, swizzled
  __shared__ bf16_t Vsb[2][4096];    // V^T tile [64 d][64 kv], dbuf, swizzled
  bf16_t* P = Plds[w];

  bf16x8 aqL[2], aqH[2];
#pragma unroll
  for (int kk = 0; kk < 2; ++kk) {
    aqL[kk] = *(const bf16x8*)(Qb + (size_t)(qrowL + lm) * 64 + kk * 32 + lg * 8);
    aqH[kk] = *(const bf16x8*)(Qb + (size_t)(qrowH + lm) * 64 + kk * 32 + lg * 8);
  }

  float lL = 0.f, lH = 0.f;
  f32x4 zero = {0.f, 0.f, 0.f, 0.f};
  f32x4 accL[4], accH[4];
#pragma unroll
  for (int nd = 0; nd < 4; ++nd) { accL[nd] = zero; accH[nd] = zero; }

  const int sLend = hL * 2 + (wg >> 1);  // inclusive diagonal 32-kv step
  const int sHend = hH * 2 + (wg >> 1);
  const int tmax = 31 - 2 * j;           // group-0's last tile (loop uniform)

  // stage one 64-kv K/V tile; each of the 8 waves loads 1 chunk of K + V
  auto stage = [&](int buf, int t) {
    const int kv0 = t * 64;
    int c = w;                      // chunk 0..7 (8 rows x 128B)
    int r = c * 8 + (lane >> 3);    // tile row 0..63
    int gs = (lane & 7) ^ (r & 7);  // inverse-swizzled source granule
    gload_lds16(Kb + (size_t)(kv0 + r) * 64 + gs * 8, Ksb[buf] + c * 512);
    gload_lds16(Vb + (size_t)r * S + kv0 + gs * 8, Vsb[buf] + c * 512);
  };

  stage(0, 0);
  for (int t = 0; t <= tmax; ++t) {
    if (t < tmax) {
      stage((t + 1) & 1, t + 1);
      asm volatile("s_waitcnt vmcnt(2)" ::: "memory");  // drain tile t only
    } else {
      asm volatile("s_waitcnt vmcnt(0)" ::: "memory");
    }
    __builtin_amdgcn_s_barrier();
    asm volatile("" ::: "memory");
    const bf16_t* Ks_ = Ksb[t & 1];
    const bf16_t* Vs_ = Vsb[t & 1];
#pragma unroll
    for (int s32 = 0; s32 < 2; ++s32) {
      const int step = t * 2 + s32;
      const bool actH = step <= sHend;
      const bool actL = step <= sLend;
      if (actH) {
        bf16x8 kf[2][2], bv[4];
#pragma unroll
        for (int nt = 0; nt < 2; ++nt)
#pragma unroll
          for (int kk = 0; kk < 2; ++kk)
            kf[nt][kk] = lds_frag(Ks_, s32 * 32 + nt * 16 + lm, kk * 4 + lg);
#pragma unroll
        for (int nd = 0; nd < 4; ++nd)
          bv[nd] = lds_frag(Vs_, nd * 16 + lm, s32 * 4 + lg);
        // QK^T transposed: C[kv][q], lane holds kv = nt*16+lg*4+r for q = lm
        __builtin_amdgcn_s_setprio(1);
        f32x4 sh0 = MFMA16(kf[0][0], aqH[0], zero);
        sh0 = MFMA16(kf[0][1], aqH[1], sh0);
        f32x4 sh1 = MFMA16(kf[1][0], aqH[0], zero);
        sh1 = MFMA16(kf[1][1], aqH[1], sh1);
        f32x4 sl0, sl1;
        if (actL) {
          sl0 = MFMA16(kf[0][0], aqL[0], zero);
          sl0 = MFMA16(kf[0][1], aqL[1], sl0);
          sl1 = MFMA16(kf[1][0], aqL[0], zero);
          sl1 = MFMA16(kf[1][1], aqL[1], sl1);
        }
        __builtin_amdgcn_s_setprio(0);
        sm_step(sh0, sh1, lH, P, 4, step == sHend, lm, lg, qrel);
        if (actL) sm_step(sl0, sl1, lL, P, 0, step == sLend, lm, lg, qrel);
        asm volatile("s_waitcnt lgkmcnt(0)" ::: "memory");
        __builtin_amdgcn_s_setprio(1);
        pv_step(P, 4, bv, accH, lm, lg);
        if (actL) pv_step(P, 0, bv, accL, lm, lg);
        __builtin_amdgcn_s_setprio(0);
      }
    }
    asm volatile("" ::: "memory");
    __builtin_amdgcn_s_barrier();   // all reads of buf[t&1] done before reuse
    asm volatile("" ::: "memory");
  }

  // epilogue l-reduction across the 4-lane group {l, l^16, l^32, l^48}
  float lsH = lH, lsL = lL;
  lsH += __shfl_xor(lsH, 16); lsH += __shfl_xor(lsH, 32);
  lsL += __shfl_xor(lsL, 16); lsL += __shfl_xor(lsL, 32);
  const float rlH = 1.f / lsH, rlL = 1.f / lsL;
#pragma unroll
  for (int nd = 0; nd < 4; ++nd) {
    uint2 oH, oL;
    oH.x = cvt_pk_bf16(accH[nd][0] * rlH, accH[nd][1] * rlH);
    oH.y = cvt_pk_bf16(accH[nd][2] * rlH, accH[nd][3] * rlH);
    oL.x = cvt_pk_bf16(accL[nd][0] * rlL, accL[nd][1] * rlL);
    oL.y = cvt_pk_bf16(accL[nd][2] * rlL, accL[nd][3] * rlL);
    size_t col = (size_t)(h * 64 + nd * 16 + lg * 4);
    *(uint2*)(Aout + ((size_t)(b * 2048 + qrowH + lm)) * 1024 + col) = oH;
    *(uint2*)(Aout + ((size_t)(b * 2048 + qrowL + lm)) * 1024 + col) = oL;
  }
}

// ---------------- launch -----------------
extern "C" void kernel_launch(void* const* d_in, const int* in_sizes, int n_in,
                              void* d_out, int out_size, void* d_ws, size_t ws_size,
                              hipStream_t stream) {
  (void)in_sizes; (void)n_in; (void)out_size; (void)ws_size;
  const float* x  = (const float*)d_in[0];
  const float* Wq = (const float*)d_in[1];
  const float* Wk = (const float*)d_in[2];
  const float* Wv = (const float*)d_in[3];
  const float* Wo = (const float*)d_in[4];

  char* w = (char*)d_ws;
  bf16_t* xb    = (bf16_t*)(w);                 // 8192x1024      (16 MiB)
  bf16_t* wb    = (bf16_t*)(w + 16777216);      // 3072x1024      (6 MiB)
  bf16_t* wob   = (bf16_t*)(w + 23068672);      // 1024x1024      (2 MiB)
  bf16_t* qb    = (bf16_t*)(w + 25165824);      // Q [B,H,S,64]   (16 MiB)
  bf16_t* kb    = (bf16_t*)(w + 41943040);      // K [B,H,S,64]   (16 MiB)
  bf16_t* vtb   = (bf16_t*)(w + 58720256);      // V^T [B,H,64,S] (16 MiB)
  bf16_t* attnb = (bf16_t*)(w + 75497472);      // [B,S,1024]     (16 MiB)

  cvt_all<<<dim3(256, 12), 256, 0, stream>>>(x, Wq, Wk, Wv, Wo, xb, wb, wob);

  // QKV projection: M=8192, N=3072, K=1024 (1536 blocks, m-fast XCD swizzle)
  gemm_bt<0><<<dim3(1536), 256, 0, stream>>>(xb, wb, qb, kb, vtb, nullptr);
  // causal attention (adjacent pairs/block, 8 waves, dbuf staged K/V)
  attn_fwd<<<dim3(512), 512, 0, stream>>>(qb, kb, vtb, attnb);
  // output projection: M=8192, N=1024, K=1024 (512 blocks, m-fast XCD swizzle)
  gemm_bt<1><<<dim3(512), 256, 0, stream>>>(attnb, wob, nullptr, nullptr, nullptr,
                                            (float*)d_out);
}

// Round 16
// 160.955 us; speedup vs baseline: 1.1194x; 1.1194x over previous
//
#include <hip/hip_runtime.h>
#include <cstdint>
#include <cstddef>

typedef __bf16 bf16_t;
typedef __bf16 bf16x8 __attribute__((ext_vector_type(8)));
typedef float f32x4 __attribute__((ext_vector_type(4)));

#define MFMA16(a, b, c) __builtin_amdgcn_mfma_f32_16x16x32_bf16((a), (b), (c), 0, 0, 0)

// ---------------- fused f32 -> bf16 conversion (RNE), one launch ----------
// grid.y: 0..7 = x chunks (1M floats each), 8..10 = Wq/Wk/Wv, 11 = Wo.
__global__ __launch_bounds__(256) void cvt_all(const float* __restrict__ x,
                                               const float* __restrict__ Wq,
                                               const float* __restrict__ Wk,
                                               const float* __restrict__ Wv,
                                               const float* __restrict__ Wo,
                                               bf16_t* __restrict__ xb,
                                               bf16_t* __restrict__ wb,
                                               bf16_t* __restrict__ wob) {
  const int y = blockIdx.y;
  const float* src;
  bf16_t* dst;
  if (y < 8) {
    src = x + (size_t)y * 1048576;
    dst = xb + (size_t)y * 1048576;
  } else if (y == 8)  { src = Wq; dst = wb; }
  else if (y == 9)    { src = Wk; dst = wb + 1048576; }
  else if (y == 10)   { src = Wv; dst = wb + 2097152; }
  else                { src = Wo; dst = wob; }
  const int n4 = 262144;
  int stride = gridDim.x * blockDim.x;
  for (int i = blockIdx.x * blockDim.x + threadIdx.x; i < n4; i += stride) {
    float4 v = *(const float4*)(src + (size_t)i * 4);
    ushort4 o;
    o.x = __builtin_bit_cast(unsigned short, (bf16_t)v.x);
    o.y = __builtin_bit_cast(unsigned short, (bf16_t)v.y);
    o.z = __builtin_bit_cast(unsigned short, (bf16_t)v.z);
    o.w = __builtin_bit_cast(unsigned short, (bf16_t)v.w);
    *(ushort4*)(dst + (size_t)i * 4) = o;
  }
}

// ---------------- shared helpers ----------------
__device__ __forceinline__ void gload_lds16(const bf16_t* g, bf16_t* lds) {
  __builtin_amdgcn_global_load_lds(
      (const __attribute__((address_space(1))) unsigned int*)g,
      (__attribute__((address_space(3))) unsigned int*)lds, 16, 0, 0);
}

// tile pitch = 128 B per row; 16B granules XOR-swizzled by (row&7)
__device__ __forceinline__ bf16x8 lds_frag(const bf16_t* tile, int row, int g) {
  int byte = row * 128 + ((g ^ (row & 7)) << 4);
  return *(const bf16x8*)((const char*)tile + byte);
}

__device__ __forceinline__ unsigned cvt_pk_bf16(float lo, float hi) {
  unsigned r;
  asm("v_cvt_pk_bf16_f32 %0, %1, %2" : "=v"(r) : "v"(lo), "v"(hi));
  return r;
}

// ---------------- GEMM: C[M,N] = A[M,K] * B[N,K]^T, bf16 in, f32 acc ------
// r11-verified staging (A+B via gload_lds + XOR swizzle) + r13-verified
// within-XCD m-FAST ordering: each XCD owns 8 contiguous M-rows; the
// concurrent block window spans 8 M x ~6 N tiles -> A(2MB)+B(1.5MB) fit
// the 4MB per-XCD L2 (FETCH 84 -> 49MB measured).
template <int EPI>
__global__ __launch_bounds__(256)
void gemm_bt(const bf16_t* __restrict__ A, const bf16_t* __restrict__ Bm,
             bf16_t* __restrict__ Qo, bf16_t* __restrict__ Ko,
             bf16_t* __restrict__ Vto, float* __restrict__ Co) {
  const int K = 1024;
  __shared__ bf16_t As[128 * 64];
  __shared__ bf16_t Bs[128 * 64];
  const int wave = threadIdx.x >> 6, lane = threadIdx.x & 63;
  const int lm = lane & 15, lg = lane >> 4;
  const int wm = wave >> 1, wn = wave & 1;

  // bijective: xcd 0..7 owns M-rows [xcd*8, xcd*8+8), walked m-fastest
  const int xcd = blockIdx.x & 7;
  const int local = blockIdx.x >> 3;
  const int tm = (xcd * 8 + (local & 7)) * 128;
  const int tn = (local >> 3) * 128;

  f32x4 zero = {0.f, 0.f, 0.f, 0.f};
  f32x4 acc[4][4];
#pragma unroll
  for (int i = 0; i < 4; ++i)
#pragma unroll
    for (int j = 0; j < 4; ++j) acc[i][j] = zero;

  const int srow = lane >> 3;
  const int gs = lane & 7;

  for (int k0 = 0; k0 < K; k0 += 64) {
#pragma unroll
    for (int c = 0; c < 4; ++c) {
      int cc = wave * 4 + c;
      int row = cc * 8 + srow;
      int gsrc = gs ^ (row & 7);
      gload_lds16(A + (size_t)(tm + row) * K + k0 + gsrc * 8, &As[cc * 512]);
      gload_lds16(Bm + (size_t)(tn + row) * K + k0 + gsrc * 8, &Bs[cc * 512]);
    }
    __syncthreads();
#pragma unroll
    for (int kk = 0; kk < 2; ++kk) {
      bf16x8 af[4], bfr[4];
#pragma unroll
      for (int i = 0; i < 4; ++i) af[i] = lds_frag(As, wm * 64 + i * 16 + lm, kk * 4 + lg);
#pragma unroll
      for (int i = 0; i < 4; ++i) bfr[i] = lds_frag(Bs, wn * 64 + i * 16 + lm, kk * 4 + lg);
#pragma unroll
      for (int mi = 0; mi < 4; ++mi)
#pragma unroll
        for (int ni = 0; ni < 4; ++ni)
          acc[mi][ni] = MFMA16(af[mi], bfr[ni], acc[mi][ni]);
    }
    __syncthreads();
  }

#pragma unroll
  for (int mi = 0; mi < 4; ++mi) {
#pragma unroll
    for (int ni = 0; ni < 4; ++ni) {
      const int m0 = tm + wm * 64 + mi * 16 + lg * 4;  // 4-aligned, r = 0..3
      const int n = tn + wn * 64 + ni * 16 + lm;
      if (EPI == 0) {
        int which = n >> 10, rem = n & 1023;
        int hh = rem >> 6, d = rem & 63;
        int bb = m0 >> 11, s0 = m0 & 2047;  // all 4 r share bb (4 | 2048)
        size_t bh = (size_t)bb * 16 + hh;
        if (which == 2) {
          // V^T: the 4 r-values are consecutive in s -> one 8B store
          uint2 pw;
          pw.x = cvt_pk_bf16(acc[mi][ni][0], acc[mi][ni][1]);
          pw.y = cvt_pk_bf16(acc[mi][ni][2], acc[mi][ni][3]);
          *(uint2*)(Vto + (bh * 64 + d) * 2048 + s0) = pw;
        } else {
#pragma unroll
          for (int r = 0; r < 4; ++r) {
            float v = acc[mi][ni][r];
            if (which == 0)
              Qo[(bh * 2048 + s0 + r) * 64 + d] = (bf16_t)(v * 0.18033688011112042f);
            else
              Ko[(bh * 2048 + s0 + r) * 64 + d] = (bf16_t)v;
          }
        }
      } else {
#pragma unroll
        for (int r = 0; r < 4; ++r) Co[(size_t)(m0 + r) * 1024 + n] = acc[mi][ni][r];
      }
    }
  }
}

// ---------------- causal flash attention, swapped-QK^T layout ------------
// r14-verified (best: 161.4us total): 8-wave blocks, pair-groups p=j and
// p=j+8 sharing LDS-staged K/V, double buffer, counted vmcnt, raw
// barriers, plain-exp2 softmax. 48KB LDS. No setprio (hurts barrier-
// lockstep structures, r15 post-mortem / m190).
__device__ __forceinline__ void sm_step(const f32x4& s0, const f32x4& s1,
                                        float& l_run, bf16_t* P, int gbase,
                                        bool diag, int lm, int lg, int qrel) {
  float tv[2][4];
#pragma unroll
  for (int nt = 0; nt < 2; ++nt)
#pragma unroll
    for (int r = 0; r < 4; ++r) {
      float v = nt ? s1[r] : s0[r];
      if (diag && (nt * 16 + lg * 4 + r > qrel)) v = -3.0e38f;
      tv[nt][r] = v;
    }
#pragma unroll
  for (int nt = 0; nt < 2; ++nt) {
    float p0 = __builtin_amdgcn_exp2f(tv[nt][0]);
    float p1 = __builtin_amdgcn_exp2f(tv[nt][1]);
    float p2 = __builtin_amdgcn_exp2f(tv[nt][2]);
    float p3 = __builtin_amdgcn_exp2f(tv[nt][3]);
    l_run += (p0 + p1) + (p2 + p3);  // per-lane partial; reduced in epilogue
    uint2 pw;
    pw.x = cvt_pk_bf16(p0, p1);
    pw.y = cvt_pk_bf16(p2, p3);
    int gr = (gbase + nt * 2 + (lg >> 1)) ^ (lm & 7);
    *(uint2*)((char*)P + lm * 128 + gr * 16 + (lg & 1) * 8) = pw;
  }
}

__device__ __forceinline__ void pv_step(const bf16_t* P, int gbase, const bf16x8 bv[4],
                                        f32x4* acc, int lm, int lg) {
  int gr = (gbase + lg) ^ (lm & 7);
  bf16x8 pf = *(const bf16x8*)((const char*)P + lm * 128 + gr * 16);
#pragma unroll
  for (int nd = 0; nd < 4; ++nd) acc[nd] = MFMA16(bv[nd], pf, acc[nd]);
}

__global__ __launch_bounds__(512, 8)
void attn_fwd(const bf16_t* __restrict__ Q, const bf16_t* __restrict__ K,
              const bf16_t* __restrict__ Vt, bf16_t* __restrict__ Aout) {
  const int S = 2048;
  const int i = blockIdx.x;
  // XCD-locality decode: the 8 j-blocks of one bh land on the same XCD
  const int bh = (i & 7) * 8 + ((i >> 3) & 7);
  const int j = i >> 6;            // 0..7
  const int b = bh >> 4, h = bh & 15;
  const int w = threadIdx.x >> 6, lane = threadIdx.x & 63;
  const int lm = lane & 15, lg = lane >> 4;
  const int g = w >> 2;            // pair-group: waves 0-3 -> p=j, 4-7 -> p=j+8
  const int wg = w & 3;            // wave-in-group (16 q-rows each)
  const int p = j + 8 * g;         // pair 0..15
  const int hL = p, hH = 31 - p;   // paired 64-row q-tiles (balanced work)
  const int qrowL = hL * 64 + wg * 16;
  const int qrowH = hH * 64 + wg * 16;
  const int qrel = ((wg & 1) << 4) + lm;  // q - kv0 at the diagonal step

  const bf16_t* Qb = Q + (size_t)bh * S * 64;
  const bf16_t* Kb = K + (size_t)bh * S * 64;
  const bf16_t* Vb = Vt + (size_t)bh * 64 * S;

  __shared__ bf16_t Plds[8][1024];   // per-wave P; L = granules 0-3, H = 4-7
  __shared__ bf16_t Ksb[2][4096];    // K tile [64 kv][64 d], dbuf, swizzled
  __shared__ bf16_t Vsb[2][4096];    // V^T tile [64 d][64 kv], dbuf, swizzled
  bf16_t* P = Plds[w];

  bf16x8 aqL[2], aqH[2];
#pragma unroll
  for (int kk = 0; kk < 2; ++kk) {
    aqL[kk] = *(const bf16x8*)(Qb + (size_t)(qrowL + lm) * 64 + kk * 32 + lg * 8);
    aqH[kk] = *(const bf16x8*)(Qb + (size_t)(qrowH + lm) * 64 + kk * 32 + lg * 8);
  }

  float lL = 0.f, lH = 0.f;
  f32x4 zero = {0.f, 0.f, 0.f, 0.f};
  f32x4 accL[4], accH[4];
#pragma unroll
  for (int nd = 0; nd < 4; ++nd) { accL[nd] = zero; accH[nd] = zero; }

  const int sLend = hL * 2 + (wg >> 1);  // inclusive diagonal 32-kv step
  const int sHend = hH * 2 + (wg >> 1);
  const int tmax = 31 - j;               // group-0's last tile (loop uniform)

  // stage one 64-kv K/V tile; each of the 8 waves loads 1 chunk of K + V
  auto stage = [&](int buf, int t) {
    const int kv0 = t * 64;
    int c = w;                      // chunk 0..7 (8 rows x 128B)
    int r = c * 8 + (lane >> 3);    // tile row 0..63
    int gs = (lane & 7) ^ (r & 7);  // inverse-swizzled source granule
    gload_lds16(Kb + (size_t)(kv0 + r) * 64 + gs * 8, Ksb[buf] + c * 512);
    gload_lds16(Vb + (size_t)r * S + kv0 + gs * 8, Vsb[buf] + c * 512);
  };

  stage(0, 0);
  for (int t = 0; t <= tmax; ++t) {
    if (t < tmax) {
      stage((t + 1) & 1, t + 1);
      asm volatile("s_waitcnt vmcnt(2)" ::: "memory");  // drain tile t only
    } else {
      asm volatile("s_waitcnt vmcnt(0)" ::: "memory");
    }
    __builtin_amdgcn_s_barrier();
    asm volatile("" ::: "memory");
    const bf16_t* Ks_ = Ksb[t & 1];
    const bf16_t* Vs_ = Vsb[t & 1];
#pragma unroll
    for (int s32 = 0; s32 < 2; ++s32) {
      const int step = t * 2 + s32;
      const bool actH = step <= sHend;
      const bool actL = step <= sLend;
      if (actH) {
        bf16x8 kf[2][2], bv[4];
#pragma unroll
        for (int nt = 0; nt < 2; ++nt)
#pragma unroll
          for (int kk = 0; kk < 2; ++kk)
            kf[nt][kk] = lds_frag(Ks_, s32 * 32 + nt * 16 + lm, kk * 4 + lg);
#pragma unroll
        for (int nd = 0; nd < 4; ++nd)
          bv[nd] = lds_frag(Vs_, nd * 16 + lm, s32 * 4 + lg);
        // QK^T transposed: C[kv][q], lane holds kv = nt*16+lg*4+r for q = lm
        f32x4 sh0 = MFMA16(kf[0][0], aqH[0], zero);
        sh0 = MFMA16(kf[0][1], aqH[1], sh0);
        f32x4 sh1 = MFMA16(kf[1][0], aqH[0], zero);
        sh1 = MFMA16(kf[1][1], aqH[1], sh1);
        f32x4 sl0, sl1;
        if (actL) {
          sl0 = MFMA16(kf[0][0], aqL[0], zero);
          sl0 = MFMA16(kf[0][1], aqL[1], sl0);
          sl1 = MFMA16(kf[1][0], aqL[0], zero);
          sl1 = MFMA16(kf[1][1], aqL[1], sl1);
        }
        sm_step(sh0, sh1, lH, P, 4, step == sHend, lm, lg, qrel);
        if (actL) sm_step(sl0, sl1, lL, P, 0, step == sLend, lm, lg, qrel);
        asm volatile("s_waitcnt lgkmcnt(0)" ::: "memory");
        pv_step(P, 4, bv, accH, lm, lg);
        if (actL) pv_step(P, 0, bv, accL, lm, lg);
      }
    }
    asm volatile("" ::: "memory");
    __builtin_amdgcn_s_barrier();   // all reads of buf[t&1] done before reuse
    asm volatile("" ::: "memory");
  }

  // epilogue l-reduction across the 4-lane group {l, l^16, l^32, l^48}
  float lsH = lH, lsL = lL;
  lsH += __shfl_xor(lsH, 16); lsH += __shfl_xor(lsH, 32);
  lsL += __shfl_xor(lsL, 16); lsL += __shfl_xor(lsL, 32);
  const float rlH = 1.f / lsH, rlL = 1.f / lsL;
#pragma unroll
  for (int nd = 0; nd < 4; ++nd) {
    uint2 oH, oL;
    oH.x = cvt_pk_bf16(accH[nd][0] * rlH, accH[nd][1] * rlH);
    oH.y = cvt_pk_bf16(accH[nd][2] * rlH, accH[nd][3] * rlH);
    oL.x = cvt_pk_bf16(accL[nd][0] * rlL, accL[nd][1] * rlL);
    oL.y = cvt_pk_bf16(accL[nd][2] * rlL, accL[nd][3] * rlL);
    size_t col = (size_t)(h * 64 + nd * 16 + lg * 4);
    *(uint2*)(Aout + ((size_t)(b * 2048 + qrowH + lm)) * 1024 + col) = oH;
    *(uint2*)(Aout + ((size_t)(b * 2048 + qrowL + lm)) * 1024 + col) = oL;
  }
}

// ---------------- launch -----------------
extern "C" void kernel_launch(void* const* d_in, const int* in_sizes, int n_in,
                              void* d_out, int out_size, void* d_ws, size_t ws_size,
                              hipStream_t stream) {
  (void)in_sizes; (void)n_in; (void)out_size; (void)ws_size;
  const float* x  = (const float*)d_in[0];
  const float* Wq = (const float*)d_in[1];
  const float* Wk = (const float*)d_in[2];
  const float* Wv = (const float*)d_in[3];
  const float* Wo = (const float*)d_in[4];

  char* w = (char*)d_ws;
  bf16_t* xb    = (bf16_t*)(w);                 // 8192x1024      (16 MiB)
  bf16_t* wb    = (bf16_t*)(w + 16777216);      // 3072x1024      (6 MiB)
  bf16_t* wob   = (bf16_t*)(w + 23068672);      // 1024x1024      (2 MiB)
  bf16_t* qb    = (bf16_t*)(w + 25165824);      // Q [B,H,S,64]   (16 MiB)
  bf16_t* kb    = (bf16_t*)(w + 41943040);      // K [B,H,S,64]   (16 MiB)
  bf16_t* vtb   = (bf16_t*)(w + 58720256);      // V^T [B,H,64,S] (16 MiB)
  bf16_t* attnb = (bf16_t*)(w + 75497472);      // [B,S,1024]     (16 MiB)

  cvt_all<<<dim3(128, 12), 256, 0, stream>>>(x, Wq, Wk, Wv, Wo, xb, wb, wob);

  // QKV projection: M=8192, N=3072, K=1024 (1536 blocks, m-fast XCD swizzle)
  gemm_bt<0><<<dim3(1536), 256, 0, stream>>>(xb, wb, qb, kb, vtb, nullptr);
  // causal attention (2 pairs/block, 8 waves, dbuf staged K/V)
  attn_fwd<<<dim3(512), 512, 0, stream>>>(qb, kb, vtb, attnb);
  // output projection: M=8192, N=1024, K=1024 (512 blocks, m-fast XCD swizzle)
  gemm_bt<1><<<dim3(512), 256, 0, stream>>>(attnb, wob, nullptr, nullptr, nullptr,
                                            (float*)d_out);
}